// Round 5
// baseline (1074.164 us; speedup 1.0000x reference)
//
#include <hip/hip_runtime.h>
#include <cstdint>
#include <cstddef>

#define T_LEN 16384
#define BATCH 8
#define NLAYER 9

typedef _Float16 f16;
typedef __attribute__((ext_vector_type(8))) _Float16 f16x8;
typedef __attribute__((ext_vector_type(4))) float f32x4;
#define MFMA_F16 __builtin_amdgcn_mfma_f32_16x16x32_f16

// async global->LDS DMA, 16 B per lane (dst = wave-uniform base + lane*16)
__device__ __forceinline__ void stage16(const f16* g, f16* l) {
    __builtin_amdgcn_global_load_lds(
        (const __attribute__((address_space(1))) unsigned int*)g,
        (__attribute__((address_space(3))) unsigned int*)l, 16, 0, 0);
}

__device__ __forceinline__ float fast_tanh(float x) {
    return 1.0f - 2.0f / (__expf(2.0f * x) + 1.0f);
}

// ---------------------------------------------------------------------------
// Weight prepack to fp16.
//  wA: [L][2 jh][12 ch][128 row][32 k], pre-swizzled per row (slot i holds
//    logical k-group i ^ ((row>>1)&3)) so gate_kernel's LINEAR staging copy
//    reproduces the swizzled LDS image its bswz ds_reads expect.
//    jh-half row r: r<64 -> filter jh*64+r ; r>=64 -> gate 128+jh*64+(r-64).
//  wB: [L][4 ch][256 n][32 k] linear (out_kernel reads direct from L2).
// ---------------------------------------------------------------------------
__global__ __launch_bounds__(256) void prep_weights(
    const float* __restrict__ cw, const float* __restrict__ ow,
    const float* __restrict__ o1w, f16* __restrict__ wA, f16* __restrict__ wB)
{
    int n = blockIdx.x * 256 + threadIdx.x;
    const int NA = NLAYER * 2 * 12 * 128 * 32;   // 884736
    const int NB = NLAYER * 4 * 256 * 32;        // 294912
    if (n < NA) {
        int kp = n & 31; int q = n >> 5;
        int row = q & 127; q >>= 7;
        int ch = q % 12; q /= 12;
        int jh = q & 1; int l = q >> 1;
        int key = (row >> 1) & 3;
        int i = kp >> 3, jj = kp & 7;
        int kpl = (i ^ key) * 8 + jj;            // logical k within chunk
        int tap = ch >> 2;
        int r = (ch & 3) * 32 + kpl;             // input channel
        int n256 = (row < 64) ? (jh * 64 + row) : (128 + jh * 64 + (row - 64));
        wA[n] = (f16)cw[((size_t)(l * 256 + n256) * 128 + r) * 3 + tap];
    } else if (n < NA + NB) {
        int m = n - NA;
        int kp = m & 31; int q = m >> 5;
        int c = q & 255; q >>= 8;
        int ch = q & 3; int l = q >> 2;
        int k = ch * 32 + kp;
        float v = (c < 128) ? ow[(size_t)(l * 128 + c) * 128 + k]
                            : o1w[(size_t)(c - 128) * 1152 + l * 128 + k];
        wB[m] = (f16)v;
    }
}

// h[b][t][r] = tanh(iw[r]*x[b][t] + ib[r]) (fp16);  acc1 zero-init (fp16)
__global__ __launch_bounds__(256) void input_init(
    const float* __restrict__ x, const float* __restrict__ iw,
    const float* __restrict__ ib,
    f16* __restrict__ h, f16* __restrict__ acc1)
{
    int n = blockIdx.x * 256 + threadIdx.x;
    int r = n & 127; int bt = n >> 7;
    h[n] = (f16)fast_tanh(iw[r] * x[bt] + ib[r]);
    acc1[n] = (f16)0.0f;
}

// ---------------------------------------------------------------------------
// gate_kernel: phase 1 + gating for one j-half. 1024 thr = 16 waves
// (mg = w>>1 splits M into 8, nw = w&1 splits the 64 z-cols into 2).
// Block tile M=256 x 128 B-rows (64 filter + 64 gate); wave tile 32 x 64-pair.
// wA jh-half (96 KB) staged ONCE into LDS, then 2 jobs of pure straight-line
// MFMA/ds_read/gating — ZERO barriers after staging (rounds 0/3/4 showed the
// 24-barrier-era structure is the stall; this removes it). acc = 32 AGPR.
// z written into the h_out buffer (same [b][t][128] shape; out_kernel reads
// rows before overwriting them — ordered by its own barrier).
// XCD map: bid%8 = batch -> each batch's h/z stays on one XCD's L2 across
// both kernels and layers.
// ---------------------------------------------------------------------------
__global__ __launch_bounds__(1024, 4) void gate_kernel(
    const f16* __restrict__ h_in, f16* __restrict__ z,
    const f16* __restrict__ wA,   // [2][12][128][32] this layer, pre-swizzled
    const float* __restrict__ cb, // conv_b [256]
    int d)
{
    __shared__ __align__(16) f16 Wl[12 * 128 * 32];   // 98304 B resident

    const int tid  = threadIdx.x;
    const int w    = tid >> 6;      // 0..15
    const int lane = tid & 63;
    const int mg   = w >> 1;        // 0..7
    const int nw   = w & 1;
    const int col  = lane & 15;
    const int quad = lane >> 4;

    const int bid = blockIdx.x;     // 512 blocks
    const int b   = bid & 7;
    const int q   = bid >> 3;       // 0..63
    const int tg  = q & 31;
    const int jh  = q >> 5;

    const f16* hb = h_in + (size_t)b * T_LEN * 128;
    f16* zb = z + (size_t)b * T_LEN * 128;
    const int bswz = (quad ^ ((col >> 1) & 3)) * 8;

    // ---- stage the 96 KB jh-half once --------------------------------------
    {
        const f16* src = wA + (size_t)jh * (12 * 128 * 32) + tid * 8;
        f16* dst = Wl + tid * 8;
#pragma unroll
        for (int i = 0; i < 6; ++i)
            stage16(src + i * 8192, dst + i * 8192);
        asm volatile("s_waitcnt vmcnt(0)" ::: "memory");
    }
    __syncthreads();   // the ONLY barrier in this kernel

#pragma unroll
    for (int j = 0; j < 2; ++j) {
        const int t0 = (tg * 2 + j) * 256;

        f32x4 acc[2][4];
#pragma unroll
        for (int mt = 0; mt < 2; ++mt)
#pragma unroll
            for (int nt = 0; nt < 4; ++nt) acc[mt][nt] = (f32x4)0.0f;

#pragma unroll
        for (int tap = 0; tap < 3; ++tap) {
            const int off = (2 - tap) * d;
            f16x8 a[2][4];
#pragma unroll
            for (int mt = 0; mt < 2; ++mt) {
                int t = t0 + mg * 32 + mt * 16 + col - off;
                if (t >= 0) {
                    const f16* hp = &hb[(size_t)t * 128 + quad * 8];
#pragma unroll
                    for (int cc = 0; cc < 4; ++cc)
                        a[mt][cc] = *(const f16x8*)&hp[cc * 32];
                } else {
#pragma unroll
                    for (int cc = 0; cc < 4; ++cc)
                        a[mt][cc] = (f16x8)(f16)0.0f;
                }
            }
#pragma unroll
            for (int kc = 0; kc < 4; ++kc) {
                const f16* Bc = Wl + (tap * 4 + kc) * 4096;
#pragma unroll
                for (int nt = 0; nt < 4; ++nt) {
                    int rowb = ((nt < 2) ? (nw * 32 + nt * 16)
                                         : (64 + nw * 32 + (nt - 2) * 16)) + col;
                    f16x8 bf = *(const f16x8*)&Bc[rowb * 32 + bswz];
                    acc[0][nt] = MFMA_F16(a[0][kc], bf, acc[0][nt], 0, 0, 0);
                    acc[1][nt] = MFMA_F16(a[1][kc], bf, acc[1][nt], 0, 0, 0);
                }
            }
        }

        // ---- gating (3-trans fused tanh*sigmoid) -> z store ----------------
#pragma unroll
        for (int ntf = 0; ntf < 2; ++ntf) {
            int jf = jh * 64 + nw * 32 + ntf * 16 + col;
            float cf = cb[jf];
            float cg = cb[jf + 128];
#pragma unroll
            for (int mt = 0; mt < 2; ++mt)
#pragma unroll
                for (int reg = 0; reg < 4; ++reg) {
                    float f = acc[mt][ntf][reg]     + cf;
                    float g = acc[mt][ntf + 2][reg] + cg;
                    float E = __builtin_amdgcn_exp2f(2.885390082f * f); // e^2f
                    float S = __builtin_amdgcn_exp2f(1.442695041f * g); // e^g
                    float zv = (E - 1.0f) * S *
                               __builtin_amdgcn_rcpf((E + 1.0f) * (S + 1.0f));
                    zb[(size_t)(t0 + mg * 32 + mt * 16 + quad * 4 + reg) * 128
                       + jf] = (f16)zv;
                }
        }
    }
}

// ---------------------------------------------------------------------------
// out_kernel: phase 2 + tail. 256 thr = 4 waves, block M=64 x N=256
// ([res 128 | o1-partial 128]), K=128. A = z direct from global (L2-warm,
// same-XCD); B = wB direct from L2. ONE barrier (tail transpose). Reads all
// of its z rows before the barrier; overwrites them with h_out after.
// ---------------------------------------------------------------------------
__global__ __launch_bounds__(256, 4) void out_kernel(
    const f16* __restrict__ h_in, f16* __restrict__ hz,  // z in / h_out out
    f16* __restrict__ acc1,
    const f16* __restrict__ wB,   // [4][256][32] linear
    const float* __restrict__ ob) // out_b [128]
{
    __shared__ __align__(16) f16 zsR[64 * 136];
    __shared__ __align__(16) f16 zsS[64 * 136];

    const int tid  = threadIdx.x;
    const int lane = tid & 63;
    const int w4   = tid >> 6;
    const int mg   = w4 & 1;
    const int ng   = w4 >> 1;
    const int col  = lane & 15;
    const int quad = lane >> 4;

    const int bid  = blockIdx.x;   // 2048
    const int b    = bid & 7;
    const int t0   = (bid >> 3) * 64;

    const f16* zb = hz + (size_t)b * T_LEN * 128;
    const f16* wBb = wB + (size_t)(ng * 64 + col) * 32 + quad * 8;

    f32x4 acc[2][8];
#pragma unroll
    for (int mt = 0; mt < 2; ++mt)
#pragma unroll
        for (int nt = 0; nt < 8; ++nt) acc[mt][nt] = (f32x4)0.0f;

#pragma unroll
    for (int ch = 0; ch < 4; ++ch) {
        f16x8 a2[2];
#pragma unroll
        for (int mt = 0; mt < 2; ++mt)
            a2[mt] = *(const f16x8*)
                &zb[(size_t)(t0 + mg * 32 + mt * 16 + col) * 128 + ch * 32 + quad * 8];
        const f16* bp = wBb + ch * 8192;
#pragma unroll
        for (int nt = 0; nt < 8; ++nt) {
            f16x8 bf = *(const f16x8*)&bp[(nt & 3) * 512 + (nt >> 2) * 4096];
            acc[0][nt] = MFMA_F16(a2[0], bf, acc[0][nt], 0, 0, 0);
            acc[1][nt] = MFMA_F16(a2[1], bf, acc[1][nt], 0, 0, 0);
        }
    }

    // ---- merged tail: res->zsR (+ob), skip->zsS ----------------------------
#pragma unroll
    for (int nt = 0; nt < 4; ++nt) {
        int n = ng * 64 + nt * 16 + col;
        float o = ob[n];
#pragma unroll
        for (int mt = 0; mt < 2; ++mt)
#pragma unroll
            for (int reg = 0; reg < 4; ++reg) {
                int r = (mg * 32 + mt * 16 + quad * 4 + reg) * 136 + n;
                zsR[r] = (f16)(acc[mt][nt][reg] + o);
                zsS[r] = (f16)acc[mt][nt + 4][reg];
            }
    }
    __syncthreads();   // also orders: all z reads done before h_out overwrite

    const int orow = tid >> 2, oseg = tid & 3;
    const size_t gb = (size_t)b * T_LEN * 128 + (size_t)(t0 + orow) * 128 + oseg * 32;
    f16x8 hv[4], av[4];
#pragma unroll
    for (int i = 0; i < 4; ++i) hv[i] = *(const f16x8*)&h_in[gb + i * 8];
#pragma unroll
    for (int i = 0; i < 4; ++i) av[i] = *(const f16x8*)&acc1[gb + i * 8];
#pragma unroll
    for (int i = 0; i < 4; ++i) {
        f16x8 rv = *(const f16x8*)&zsR[orow * 136 + oseg * 32 + i * 8];
        *(f16x8*)&hz[gb + i * 8] = hv[i] + rv;     // h_out overwrites z
    }
#pragma unroll
    for (int i = 0; i < 4; ++i) {
        f16x8 sv = *(const f16x8*)&zsS[orow * 136 + oseg * 32 + i * 8];
        *(f16x8*)&acc1[gb + i * 8] = av[i] + sv;
    }
}

// out[bt] = o2b + sum_r o2w[r] * tanh(acc1[bt][r] + o1b[r]); one wave per bt
__global__ __launch_bounds__(256) void final_kernel(
    const f16* __restrict__ acc1, const float* __restrict__ b1,
    const float* __restrict__ w2, const float* __restrict__ b2,
    float* __restrict__ out)
{
    int lane = threadIdx.x & 63;
    int w = threadIdx.x >> 6;
    int bt = blockIdx.x * 4 + w;
    float v0 = (float)acc1[(size_t)bt * 128 + lane];
    float v1 = (float)acc1[(size_t)bt * 128 + lane + 64];
    float s = w2[lane] * fast_tanh(v0 + b1[lane]) +
              w2[lane + 64] * fast_tanh(v1 + b1[lane + 64]);
#pragma unroll
    for (int k = 1; k < 64; k <<= 1) s += __shfl_xor(s, k, 64);
    if (lane == 0) out[bt] = s + b2[0];
}

extern "C" void kernel_launch(void* const* d_in, const int* in_sizes, int n_in,
                              void* d_out, int out_size, void* d_ws, size_t ws_size,
                              hipStream_t stream)
{
    const float* x   = (const float*)d_in[0];
    const float* iw  = (const float*)d_in[1];
    const float* ib  = (const float*)d_in[2];
    const float* cw  = (const float*)d_in[3];
    const float* cb  = (const float*)d_in[4];
    const float* ow  = (const float*)d_in[5];
    const float* ob  = (const float*)d_in[6];
    const float* o1w = (const float*)d_in[7];
    const float* o1b = (const float*)d_in[8];
    const float* o2w = (const float*)d_in[9];
    const float* o2b = (const float*)d_in[10];
    float* out = (float*)d_out;

    const size_t HTR = (size_t)BATCH * T_LEN * 128;   // 16777216
    f16* hA   = (f16*)d_ws;
    f16* hB   = hA + HTR;
    f16* acc1 = hB + HTR;
    f16* wAp  = acc1 + HTR;
    f16* wBp  = wAp + (size_t)NLAYER * 2 * 12 * 128 * 32;
    // total ~ 3*32 MB + 2.4 MB of ws (z lives inside the h_out buffer)

    prep_weights<<<4608, 256, 0, stream>>>(cw, ow, o1w, wAp, wBp);
    input_init<<<65536, 256, 0, stream>>>(x, iw, ib, hA, acc1);

    const int DIL[NLAYER] = {1, 2, 4, 8, 16, 32, 64, 128, 256};
    f16* hin = hA; f16* hout = hB;
    for (int l = 0; l < NLAYER; ++l) {
        gate_kernel<<<512, 1024, 0, stream>>>(
            hin, hout, wAp + (size_t)l * 2 * 12 * 128 * 32,
            cb + l * 256, DIL[l]);
        out_kernel<<<2048, 256, 0, stream>>>(
            hin, hout, acc1,
            wBp + (size_t)l * 4 * 256 * 32, ob + l * 128);
        f16* tmp = hin; hin = hout; hout = tmp;
    }
    final_kernel<<<BATCH * T_LEN / 4, 256, 0, stream>>>(acc1, o1b, o2w, o2b, out);
}

// Round 8
// 936.669 us; speedup vs baseline: 1.1468x; 1.1468x over previous
//
#include <hip/hip_runtime.h>
#include <cstdint>
#include <cstddef>

#define T_LEN 16384
#define BATCH 8
#define NLAYER 9

typedef _Float16 f16;
typedef __attribute__((ext_vector_type(8))) _Float16 f16x8;
typedef __attribute__((ext_vector_type(4))) float f32x4;
#define MFMA_F16 __builtin_amdgcn_mfma_f32_16x16x32_f16

// async global->LDS DMA, 16 B per lane (dst = wave-uniform base + lane*16)
__device__ __forceinline__ void stage16(const f16* g, f16* l) {
    __builtin_amdgcn_global_load_lds(
        (const __attribute__((address_space(1))) unsigned int*)g,
        (__attribute__((address_space(3))) unsigned int*)l, 16, 0, 0);
}

__device__ __forceinline__ float fast_tanh(float x) {
    return 1.0f - 2.0f / (__expf(2.0f * x) + 1.0f);
}

// ---------------------------------------------------------------------------
// Weight prepack to fp16, B-fragment order [n][k32-chunk].  (round-4 layout)
//  wA [12][256][32] pre-swizzled per row (slot i holds logical k-group
//  i ^ ((n>>1)&3)); rows 0-127 = filters, 128-255 = gates.
//  wB [4][256][32] linear (phase 2 reads direct from L2).
// ---------------------------------------------------------------------------
__global__ __launch_bounds__(256) void prep_weights(
    const float* __restrict__ cw, const float* __restrict__ ow,
    const float* __restrict__ o1w, f16* __restrict__ wA, f16* __restrict__ wB)
{
    int n = blockIdx.x * 256 + threadIdx.x;
    const int NA = NLAYER * 12 * 256 * 32;   // 884736
    const int NB = NLAYER * 4 * 256 * 32;    // 294912
    if (n < NA) {
        int kp = n & 31; int q = n >> 5;
        int c = q & 255; q >>= 8;
        int ch = q % 12; int l = q / 12;
        int i = kp >> 3, j = kp & 7;
        int il = i ^ ((c >> 1) & 3);
        int kpl = il * 8 + j;
        int tap = ch >> 2;
        int r = (ch & 3) * 32 + kpl;
        wA[n] = (f16)cw[((size_t)(l * 256 + c) * 128 + r) * 3 + tap];
    } else if (n < NA + NB) {
        int m = n - NA;
        int kp = m & 31; int q = m >> 5;
        int c = q & 255; q >>= 8;
        int ch = q & 3; int l = q >> 2;
        int k = ch * 32 + kp;
        float v = (c < 128) ? ow[(size_t)(l * 128 + c) * 128 + k]
                            : o1w[(size_t)(c - 128) * 1152 + l * 128 + k];
        wB[m] = (f16)v;
    }
}

// h[b][t][r] = tanh(iw[r]*x[b][t] + ib[r]) (fp16);  acc1 zero-init (fp16)
__global__ __launch_bounds__(256) void input_init(
    const float* __restrict__ x, const float* __restrict__ iw,
    const float* __restrict__ ib,
    f16* __restrict__ h, f16* __restrict__ acc1)
{
    int n = blockIdx.x * 256 + threadIdx.x;
    int r = n & 127; int bt = n >> 7;
    h[n] = (f16)fast_tanh(iw[r] * x[bt] + ib[r]);
    acc1[n] = (f16)0.0f;
}

// ---------------------------------------------------------------------------
// One layer, fused. 512 thr = 8 waves: mg = w>>2 splits M (2x32),
// nq = w&3 splits N (4x64-pair). Wave tile M=32 x N=64-pair -> acc[2][4] =
// 32 AGPR. launch_bounds(512,6) -> 6 waves/SIMD = 24 waves/CU (every prior
// round was pinned at 4/SIMD with MfmaUtil ~16% in ALL structures; this
// round varies ONLY occupancy).
//
// A-LOAD PLACEMENT RULE (round-6 bug, do not reintroduce): loadA(tap)
// overwrites the a[][] register array, so in PROGRAM ORDER it must come
// after the last MFMA using the previous tap (era tap*8-1) and before the
// first MFMA of the new tap (era tap*8). It sits at the TOP of era tap*8.
// The compiler auto-inserts the waitcnt protecting a->MFMA; cost is one
// exposed A-load per tap boundary (round-4 paid the same at 82 us).
//
// vmcnt ledger (1 stage16/thread/era, DMA issued 3 eras ahead):
//   prologue: loadA(0); DMA0,1,2; vmcnt(2) retires A+DMA0, keeps DMA1,2.
//   era hc: issue DMA(hc+3); MFMA buf(hc&3); vmcnt(2) retires DMA(hc+1);
//   barrier. Eras 8/16: compiler pre-MFMA A-wait over-drains 2 DMAs
//   (harmless; later vmcnt(2) trivially satisfied). Tail: 21->vmcnt(1),
//   22->vmcnt(0), 23 none.
// DO NOT tighten the reg cap below 6 waves' 85: round-1's 64-reg cap
// spilled accumulators (2 GB scratch/dispatch, 6x regression).
// ---------------------------------------------------------------------------
__global__ __launch_bounds__(512, 6) void layer_kernel(
    const f16* __restrict__ h_in, f16* __restrict__ h_out,
    f16* __restrict__ acc1,
    const f16* __restrict__ wA,   // [12][256][32] this layer (pre-swizzled)
    const f16* __restrict__ wB,   // [4][256][32]  this layer (linear)
    const float* __restrict__ cb, // conv_b [256]
    const float* __restrict__ ob, // out_b  [128]
    int d)
{
    __shared__ __align__(16) char smem_raw[34816];
    f16* const Bsm = (f16*)smem_raw;            // phase 1: 4 bufs x 4096 f16
    f16* const zsR = (f16*)smem_raw;            // z, then res: [64][136]
    f16* const zsS = (f16*)smem_raw + 8704;     // skip:        [64][136]

    const int tid  = threadIdx.x;
    const int lane = tid & 63;
    const int w    = tid >> 6;      // 0..7
    const int mg   = w >> 2;        // 0..1  (M half)
    const int nq   = w & 3;         // 0..3  (N quarter)
    const int col  = lane & 15;
    const int quad = lane >> 4;
    const int b    = blockIdx.y;
    const int bx   = blockIdx.x;
    const int xt   = ((bx & 7) << 5) | (bx >> 3);   // XCD-chunked swizzle
    const int t0   = xt * 64;

    const f16* hb = h_in + (size_t)b * T_LEN * 128;
    const int bswz = (quad ^ ((col >> 1) & 3)) * 8;
    const int lrow = nq * 32 + col;   // local B-row base within 128-row half

    f32x4 acc[2][4];
#pragma unroll
    for (int mt = 0; mt < 2; ++mt)
#pragma unroll
        for (int nt = 0; nt < 4; ++nt) acc[mt][nt] = (f32x4)0.0f;

    f16x8 a[2][4];
    // unconditional A-load (uniform vmem count) + per-lane zero select
    auto loadA = [&](int tap) {
        const int off = (2 - tap) * d;
#pragma unroll
        for (int mt = 0; mt < 2; ++mt) {
            int t = t0 + mg * 32 + mt * 16 + col - off;
            int tc = t < 0 ? 0 : t;
            const f16* hp = &hb[(size_t)tc * 128 + quad * 8];
#pragma unroll
            for (int cc = 0; cc < 4; ++cc) {
                f16x8 v = *(const f16x8*)&hp[cc * 32];
                a[mt][cc] = (t >= 0) ? v : (f16x8)(f16)0.0f;
            }
        }
    };

    // ---------------- Phase 1: pre = h * WA, 24 half-chunk eras --------------
    {   // prologue: A tap0 first (oldest in queue), then DMA half-chunks 0,1,2
        loadA(0);
        __builtin_amdgcn_sched_barrier(0);
        stage16(wA + tid * 8,        Bsm + tid * 8);
        stage16(wA + 4096 + tid * 8, Bsm + 4096 + tid * 8);
        stage16(wA + 8192 + tid * 8, Bsm + 8192 + tid * 8);
        __builtin_amdgcn_sched_barrier(0);
        // queue {A x8, DMA0, DMA1, DMA2}: retire A + DMA0, keep DMA1,2
        asm volatile("s_waitcnt vmcnt(2)" ::: "memory");
        __builtin_amdgcn_s_barrier();
        __builtin_amdgcn_sched_barrier(0);
    }

#pragma unroll
    for (int hc = 0; hc < 24; ++hc) {
        // tap-boundary A reload: AFTER last use of old tap (era hc-1's MFMA),
        // BEFORE this era's MFMA (program order). Compiler inserts the wait.
        if (hc == 8)  loadA(1);
        if (hc == 16) loadA(2);
        __builtin_amdgcn_sched_barrier(0);
        if (hc + 3 < 24) {          // issue DMA three eras ahead
            stage16(wA + (hc + 3) * 4096 + tid * 8,
                    Bsm + ((hc + 3) & 3) * 4096 + tid * 8);
        }
        __builtin_amdgcn_sched_barrier(0);
        const f16* bsc = Bsm + (hc & 3) * 4096;
        const int kc  = (hc >> 1) & 3;    // k-chunk within tap
        const int ntb = (hc & 1) * 2;     // even era: filters, odd: gates
#pragma unroll
        for (int ntl = 0; ntl < 2; ++ntl) {
            f16x8 bf = *(const f16x8*)&bsc[(lrow + ntl * 16) * 32 + bswz];
            acc[0][ntb + ntl] = MFMA_F16(a[0][kc], bf, acc[0][ntb + ntl], 0, 0, 0);
            acc[1][ntb + ntl] = MFMA_F16(a[1][kc], bf, acc[1][ntb + ntl], 0, 0, 0);
        }
        __builtin_amdgcn_sched_barrier(0);
        // era-end wait: guarantee DMA(hc+1) landed before next era's reads
        if (hc < 21) {
            asm volatile("s_waitcnt vmcnt(2)" ::: "memory");
        } else if (hc == 21) {
            asm volatile("s_waitcnt vmcnt(1)" ::: "memory");
        } else if (hc == 22) {
            asm volatile("s_waitcnt vmcnt(0)" ::: "memory");
        }
        if (hc < 23) __builtin_amdgcn_s_barrier();
        __builtin_amdgcn_sched_barrier(0);
    }
    __syncthreads();   // all Bsm reads done before z overlays

    // ---------------- Gating -> zsR (3-trans fused tanh*sigmoid) ------------
#pragma unroll
    for (int nt = 0; nt < 2; ++nt) {
        int j = nq * 32 + nt * 16 + col;
        float cf = cb[j];
        float cg = cb[j + 128];
#pragma unroll
        for (int mt = 0; mt < 2; ++mt)
#pragma unroll
            for (int reg = 0; reg < 4; ++reg) {
                float f = acc[mt][nt][reg]     + cf;
                float g = acc[mt][nt + 2][reg] + cg;
                float E = __builtin_amdgcn_exp2f(2.885390082f * f); // e^(2f)
                float S = __builtin_amdgcn_exp2f(1.442695041f * g); // e^(g)
                float z = (E - 1.0f) * S *
                          __builtin_amdgcn_rcpf((E + 1.0f) * (S + 1.0f));
                zsR[(mg * 32 + mt * 16 + quad * 4 + reg) * 136 + j] = (f16)z;
            }
    }
    __syncthreads();

    // ---------------- Phase 2: [res|skip] = z * WB, K=128; B from L2 --------
#pragma unroll
    for (int mt = 0; mt < 2; ++mt)
#pragma unroll
        for (int nt = 0; nt < 4; ++nt) acc[mt][nt] = (f32x4)0.0f;

    const f16* wBb = wB + (size_t)(nq * 32 + col) * 32 + quad * 8;
#pragma unroll
    for (int ch = 0; ch < 4; ++ch) {
        f16x8 a2[2];
#pragma unroll
        for (int mt = 0; mt < 2; ++mt)
            a2[mt] = *(const f16x8*)&zsR[(mg * 32 + mt * 16 + col) * 136 + ch * 32 + quad * 8];
        const f16* bp = wBb + ch * 8192;
#pragma unroll
        for (int nt = 0; nt < 4; ++nt) {
            // nt<2: res rows nq*32+nt*16 ; nt>=2: skip rows 128+nq*32+(nt-2)*16
            f16x8 bf = *(const f16x8*)&bp[(nt & 1) * 512 + (nt >> 1) * 4096];
            acc[0][nt] = MFMA_F16(a2[0], bf, acc[0][nt], 0, 0, 0);
            acc[1][nt] = MFMA_F16(a2[1], bf, acc[1][nt], 0, 0, 0);
        }
    }
    __syncthreads();   // z reads drained before res overwrites zsR

    // ---------------- Merged epilogue: res->zsR, skip->zsS, one barrier -----
#pragma unroll
    for (int nt = 0; nt < 2; ++nt) {
        int n = nq * 32 + nt * 16 + col;
        float o = ob[n];
#pragma unroll
        for (int mt = 0; mt < 2; ++mt)
#pragma unroll
            for (int reg = 0; reg < 4; ++reg) {
                int r = (mg * 32 + mt * 16 + quad * 4 + reg) * 136 + n;
                zsR[r] = (f16)(acc[mt][nt][reg] + o);
                zsS[r] = (f16)acc[mt][nt + 2][reg];
            }
    }
    __syncthreads();
    const int orow = tid >> 3, oseg = tid & 7;   // 64 rows x 8 col-groups
    const size_t gb = (size_t)b * T_LEN * 128 + (size_t)(t0 + orow) * 128 + oseg * 16;
    f16x8 hv[2], av[2];
#pragma unroll
    for (int i = 0; i < 2; ++i) hv[i] = *(const f16x8*)&h_in[gb + i * 8];
#pragma unroll
    for (int i = 0; i < 2; ++i) av[i] = *(const f16x8*)&acc1[gb + i * 8];
#pragma unroll
    for (int i = 0; i < 2; ++i) {
        f16x8 rv = *(const f16x8*)&zsR[orow * 136 + oseg * 16 + i * 8];
        *(f16x8*)&h_out[gb + i * 8] = hv[i] + rv;
    }
#pragma unroll
    for (int i = 0; i < 2; ++i) {
        f16x8 sv = *(const f16x8*)&zsS[orow * 136 + oseg * 16 + i * 8];
        *(f16x8*)&acc1[gb + i * 8] = av[i] + sv;
    }
}

// out[bt] = o2b + sum_r o2w[r] * tanh(acc1[bt][r] + o1b[r]); one wave per bt
__global__ __launch_bounds__(256) void final_kernel(
    const f16* __restrict__ acc1, const float* __restrict__ b1,
    const float* __restrict__ w2, const float* __restrict__ b2,
    float* __restrict__ out)
{
    int lane = threadIdx.x & 63;
    int w = threadIdx.x >> 6;
    int bt = blockIdx.x * 4 + w;
    float v0 = (float)acc1[(size_t)bt * 128 + lane];
    float v1 = (float)acc1[(size_t)bt * 128 + lane + 64];
    float s = w2[lane] * fast_tanh(v0 + b1[lane]) +
              w2[lane + 64] * fast_tanh(v1 + b1[lane + 64]);
#pragma unroll
    for (int k = 1; k < 64; k <<= 1) s += __shfl_xor(s, k, 64);
    if (lane == 0) out[bt] = s + b2[0];
}

extern "C" void kernel_launch(void* const* d_in, const int* in_sizes, int n_in,
                              void* d_out, int out_size, void* d_ws, size_t ws_size,
                              hipStream_t stream)
{
    const float* x   = (const float*)d_in[0];
    const float* iw  = (const float*)d_in[1];
    const float* ib  = (const float*)d_in[2];
    const float* cw  = (const float*)d_in[3];
    const float* cb  = (const float*)d_in[4];
    const float* ow  = (const float*)d_in[5];
    const float* ob  = (const float*)d_in[6];
    const float* o1w = (const float*)d_in[7];
    const float* o1b = (const float*)d_in[8];
    const float* o2w = (const float*)d_in[9];
    const float* o2b = (const float*)d_in[10];
    float* out = (float*)d_out;

    const size_t HTR = (size_t)BATCH * T_LEN * 128;   // 16777216
    f16* hA   = (f16*)d_ws;
    f16* hB   = hA + HTR;
    f16* acc1 = hB + HTR;
    f16* wAp  = acc1 + HTR;
    f16* wBp  = wAp + (size_t)NLAYER * 12 * 256 * 32;
    // total ~ 3*32 MB + 2.4 MB = ~103 MB of ws

    prep_weights<<<4608, 256, 0, stream>>>(cw, ow, o1w, wAp, wBp);
    input_init<<<65536, 256, 0, stream>>>(x, iw, ib, hA, acc1);

    const int DIL[NLAYER] = {1, 2, 4, 8, 16, 32, 64, 128, 256};
    f16* hin = hA; f16* hout = hB;
    for (int l = 0; l < NLAYER; ++l) {
        layer_kernel<<<dim3(T_LEN / 64, BATCH), 512, 0, stream>>>(
            hin, hout, acc1,
            wAp + (size_t)l * 12 * 256 * 32, wBp + (size_t)l * 4 * 256 * 32,
            cb + l * 256, ob + l * 128, DIL[l]);
        f16* tmp = hin; hin = hout; hout = tmp;
    }
    final_kernel<<<BATCH * T_LEN / 4, 256, 0, stream>>>(acc1, o1b, o2w, o2b, out);
}

// Round 9
// 749.348 us; speedup vs baseline: 1.4335x; 1.2500x over previous
//
#include <hip/hip_runtime.h>
#include <cstdint>
#include <cstddef>

#define T_LEN 16384
#define BATCH 8
#define NLAYER 9

typedef _Float16 f16;
typedef __attribute__((ext_vector_type(8))) _Float16 f16x8;
typedef __attribute__((ext_vector_type(4))) float f32x4;
#define MFMA_F16 __builtin_amdgcn_mfma_f32_16x16x32_f16

// async global->LDS DMA, 16 B per lane (dst = wave-uniform base + lane*16)
__device__ __forceinline__ void stage16(const f16* g, f16* l) {
    __builtin_amdgcn_global_load_lds(
        (const __attribute__((address_space(1))) unsigned int*)g,
        (__attribute__((address_space(3))) unsigned int*)l, 16, 0, 0);
}

__device__ __forceinline__ float fast_tanh(float x) {
    return 1.0f - 2.0f / (__expf(2.0f * x) + 1.0f);
}

// ---------------------------------------------------------------------------
// Weight prepack to fp16, B-fragment order [n][k32-chunk].  (round-4 layout)
//  wA [12][256][32] pre-swizzled per row (slot i holds logical k-group
//  i ^ ((n>>1)&3)); rows 0-127 = filters, 128-255 = gates.
//  wB [4][256][32] linear (phase 2 reads direct from L2).
// ---------------------------------------------------------------------------
__global__ __launch_bounds__(256) void prep_weights(
    const float* __restrict__ cw, const float* __restrict__ ow,
    const float* __restrict__ o1w, f16* __restrict__ wA, f16* __restrict__ wB)
{
    int n = blockIdx.x * 256 + threadIdx.x;
    const int NA = NLAYER * 12 * 256 * 32;   // 884736
    const int NB = NLAYER * 4 * 256 * 32;    // 294912
    if (n < NA) {
        int kp = n & 31; int q = n >> 5;
        int c = q & 255; q >>= 8;
        int ch = q % 12; int l = q / 12;
        int i = kp >> 3, j = kp & 7;
        int il = i ^ ((c >> 1) & 3);
        int kpl = il * 8 + j;
        int tap = ch >> 2;
        int r = (ch & 3) * 32 + kpl;
        wA[n] = (f16)cw[((size_t)(l * 256 + c) * 128 + r) * 3 + tap];
    } else if (n < NA + NB) {
        int m = n - NA;
        int kp = m & 31; int q = m >> 5;
        int c = q & 255; q >>= 8;
        int ch = q & 3; int l = q >> 2;
        int k = ch * 32 + kp;
        float v = (c < 128) ? ow[(size_t)(l * 128 + c) * 128 + k]
                            : o1w[(size_t)(c - 128) * 1152 + l * 128 + k];
        wB[m] = (f16)v;
    }
}

// h[b][t][r] = tanh(iw[r]*x[b][t] + ib[r]) (fp16);  acc1 zero-init (fp16)
__global__ __launch_bounds__(256) void input_init(
    const float* __restrict__ x, const float* __restrict__ iw,
    const float* __restrict__ ib,
    f16* __restrict__ h, f16* __restrict__ acc1)
{
    int n = blockIdx.x * 256 + threadIdx.x;
    int r = n & 127; int bt = n >> 7;
    h[n] = (f16)fast_tanh(iw[r] * x[bt] + ib[r]);
    acc1[n] = (f16)0.0f;
}

// ---------------------------------------------------------------------------
// One layer, fused. 256 thr = 4 waves (mg = w&1 splits M, ng = w>>1 splits N).
// Block tile M=64 x N=256; wave tile M=32 x N=128 (gate-paired). acc[2][8]=64
// AGPR + 64 arch VGPR = 128 -> 4 waves/SIMD. (r8 measured: raising occupancy
// to 6/SIMD with smaller tiles made it WORSE — 104 vs 82 µs. Keep 4/SIMD.)
//
// A-PREFETCH (the r9 change): a[mt][cc] for the current tap is dead after
// era 2cc+1, and the NEXT tap's cc isn't used until era 8+2cc. So tap1's cc
// loads at eras {2,4,6,8}, tap2's at {10,12,14,16} — into just-dead regs,
// zero extra VGPR, ~6 eras (~1500 cyc) of latency cover. (r4 loaded the
// whole tap at its first-use era -> 2x ~900-cyc exposed stalls. r6's bug
// was loading into LIVE regs — the dead-reg schedule here is the fix.)
//
// vmcnt ledger (2-load DMA eras, DMA issued 3 eras ahead, 2-load A eras;
// counts in LOADS): prologue N=4; e0,1: 4; e2..17: 6; e18..20: 4; e21: 2;
// e22: 0. A-loads get >=2 eras before any forced retirement.
//
// Tail: phase-2 ch0 B prefetched into regs BEFORE gating (gating VALU +
// barrier covers L2 latency); epilogue h_in/acc1 loads issued before the
// two tail barriers. 64 B/thread contiguous stores (r8: 32 B stores cost
// +40 MB WRITE_SIZE via partial-sector dirtying).
// DO NOT cap regs below 128: round-1's 64-reg cap spilled acc (6x).
// ---------------------------------------------------------------------------
__global__ __launch_bounds__(256, 4) void layer_kernel(
    const f16* __restrict__ h_in, f16* __restrict__ h_out,
    f16* __restrict__ acc1,
    const f16* __restrict__ wA,   // [12][256][32] this layer (pre-swizzled)
    const f16* __restrict__ wB,   // [4][256][32]  this layer (linear)
    const float* __restrict__ cb, // conv_b [256]
    const float* __restrict__ ob, // out_b  [128]
    int d)
{
    __shared__ __align__(16) char smem_raw[34816];
    f16* const Bsm = (f16*)smem_raw;            // phase 1: 4 bufs x 4096 f16
    f16* const zsR = (f16*)smem_raw;            // z, then res: [64][136]
    f16* const zsS = (f16*)smem_raw + 8704;     // skip:        [64][136]

    const int tid  = threadIdx.x;
    const int lane = tid & 63;
    const int w4   = tid >> 6;
    const int mg   = w4 & 1;
    const int ng   = w4 >> 1;
    const int col  = lane & 15;
    const int quad = lane >> 4;
    const int b    = blockIdx.y;
    const int bx   = blockIdx.x;
    const int xt   = ((bx & 7) << 5) | (bx >> 3);   // XCD-chunked swizzle
    const int t0   = xt * 64;

    const f16* hb = h_in + (size_t)b * T_LEN * 128;
    const int bswz = (quad ^ ((col >> 1) & 3)) * 8;

    f32x4 acc[2][8];
#pragma unroll
    for (int mt = 0; mt < 2; ++mt)
#pragma unroll
        for (int nt = 0; nt < 8; ++nt) acc[mt][nt] = (f32x4)0.0f;

    f16x8 a[2][4];
    // one k-chunk of A for one tap: 2 loads (uniform count), per-lane select
    auto loadA_cc = [&](int tap, int cc) {
        const int off = (2 - tap) * d;
#pragma unroll
        for (int mt = 0; mt < 2; ++mt) {
            int t = t0 + mg * 32 + mt * 16 + col - off;
            int tc = t < 0 ? 0 : t;
            f16x8 v = *(const f16x8*)&hb[(size_t)tc * 128 + quad * 8 + cc * 32];
            a[mt][cc] = (t >= 0) ? v : (f16x8)(f16)0.0f;
        }
    };

    // ---------------- Phase 1: pre = h * WA, 24 half-chunk eras --------------
    {   // prologue: full tap-0 A (8 loads), DMA half-chunks 0,1,2 (6 loads)
#pragma unroll
        for (int cc = 0; cc < 4; ++cc) loadA_cc(0, cc);
        __builtin_amdgcn_sched_barrier(0);
#pragma unroll
        for (int hh = 0; hh < 3; ++hh) {
            const f16* s = wA + hh * 4096 + w4 * 1024 + lane * 8;
            f16* dd = Bsm + hh * 4096 + w4 * 1024;
            stage16(s, dd); stage16(s + 512, dd + 512);
        }
        __builtin_amdgcn_sched_barrier(0);
        // queue {A x8, D0 x2, D1 x2, D2 x2}: retire A + D0, keep D1,D2
        asm volatile("s_waitcnt vmcnt(4)" ::: "memory");
        __builtin_amdgcn_s_barrier();
        __builtin_amdgcn_sched_barrier(0);
    }

#pragma unroll
    for (int hc = 0; hc < 24; ++hc) {
        // staggered A-prefetch into dead regs (see header comment)
        if (hc >= 2 && hc <= 16 && (hc & 1) == 0) {
            const int tap = (hc <= 8) ? 1 : 2;
            const int cc  = (hc <= 8) ? ((hc - 2) >> 1) : ((hc - 10) >> 1);
            loadA_cc(tap, cc);
        }
        __builtin_amdgcn_sched_barrier(0);
        if (hc + 3 < 24) {          // issue DMA three eras ahead
            const f16* s = wA + (hc + 3) * 4096 + w4 * 1024 + lane * 8;
            f16* dd = Bsm + ((hc + 3) & 3) * 4096 + w4 * 1024;
            stage16(s, dd); stage16(s + 512, dd + 512);
        }
        __builtin_amdgcn_sched_barrier(0);
        const f16* bsc = Bsm + (hc & 3) * 4096;
        const int kc    = (hc >> 1) & 3;    // k-chunk within tap
        const int nbase = (hc & 1) * 4;     // even era: filters, odd: gates
#pragma unroll
        for (int ntl = 0; ntl < 4; ++ntl) {
            int row = ng * 64 + ntl * 16 + col;   // local row within 128
            f16x8 bf = *(const f16x8*)&bsc[row * 32 + bswz];
            acc[0][nbase + ntl] = MFMA_F16(a[0][kc], bf, acc[0][nbase + ntl], 0, 0, 0);
            acc[1][nbase + ntl] = MFMA_F16(a[1][kc], bf, acc[1][nbase + ntl], 0, 0, 0);
        }
        __builtin_amdgcn_sched_barrier(0);
        // era-end wait (counts in loads; see ledger in header)
        if (hc <= 1) {
            asm volatile("s_waitcnt vmcnt(4)" ::: "memory");
        } else if (hc <= 17) {
            asm volatile("s_waitcnt vmcnt(6)" ::: "memory");
        } else if (hc <= 20) {
            asm volatile("s_waitcnt vmcnt(4)" ::: "memory");
        } else if (hc == 21) {
            asm volatile("s_waitcnt vmcnt(2)" ::: "memory");
        } else if (hc == 22) {
            asm volatile("s_waitcnt vmcnt(0)" ::: "memory");
        }
        if (hc < 23) __builtin_amdgcn_s_barrier();
        __builtin_amdgcn_sched_barrier(0);
    }
    __syncthreads();   // all Bsm reads done before z overlays

    // ---- prefetch phase-2 ch0 B-frags (independent of zs; covered by gating)
    f16x8 b0[8];
#pragma unroll
    for (int nt = 0; nt < 8; ++nt) {
        int nb = (nt < 4) ? (ng * 64 + nt * 16)
                          : (128 + ng * 64 + (nt - 4) * 16);
        b0[nt] = *(const f16x8*)&wB[(size_t)(nb + col) * 32 + quad * 8];
    }

    // ---------------- Gating -> zsR (3-trans fused tanh*sigmoid) ------------
#pragma unroll
    for (int nt = 0; nt < 4; ++nt) {
        int j = ng * 64 + nt * 16 + col;
        float cf = cb[j];
        float cg = cb[j + 128];
#pragma unroll
        for (int mt = 0; mt < 2; ++mt)
#pragma unroll
            for (int reg = 0; reg < 4; ++reg) {
                float f = acc[mt][nt][reg]     + cf;
                float g = acc[mt][nt + 4][reg] + cg;
                float E = __builtin_amdgcn_exp2f(2.885390082f * f); // e^(2f)
                float S = __builtin_amdgcn_exp2f(1.442695041f * g); // e^(g)
                float z = (E - 1.0f) * S *
                          __builtin_amdgcn_rcpf((E + 1.0f) * (S + 1.0f));
                zsR[(mg * 32 + mt * 16 + quad * 4 + reg) * 136 + j] = (f16)z;
            }
    }
    __syncthreads();

    // ---------------- Phase 2: [res|skip] = z * WB, K=128 -------------------
#pragma unroll
    for (int mt = 0; mt < 2; ++mt)
#pragma unroll
        for (int nt = 0; nt < 8; ++nt) acc[mt][nt] = (f32x4)0.0f;

#pragma unroll
    for (int ch = 0; ch < 4; ++ch) {
        f16x8 a2[2];
#pragma unroll
        for (int mt = 0; mt < 2; ++mt)
            a2[mt] = *(const f16x8*)&zsR[(mg * 32 + mt * 16 + col) * 136 + ch * 32 + quad * 8];
        const f16* wc = wB + ch * 8192;
#pragma unroll
        for (int nt = 0; nt < 8; ++nt) {
            int nb = (nt < 4) ? (ng * 64 + nt * 16)
                              : (128 + ng * 64 + (nt - 4) * 16);
            f16x8 bf = (ch == 0) ? b0[nt]
                                 : *(const f16x8*)&wc[(nb + col) * 32 + quad * 8];
            acc[0][nt] = MFMA_F16(a2[0], bf, acc[0][nt], 0, 0, 0);
            acc[1][nt] = MFMA_F16(a2[1], bf, acc[1][nt], 0, 0, 0);
        }
    }

    // ---- epilogue global loads issued HERE: covered by 2 barriers + writes
    const int orow = tid >> 2, oseg = tid & 3;
    const size_t gb = (size_t)b * T_LEN * 128 + (size_t)(t0 + orow) * 128 + oseg * 32;
    f16x8 hv[4], av[4];
#pragma unroll
    for (int i = 0; i < 4; ++i) hv[i] = *(const f16x8*)&h_in[gb + i * 8];
#pragma unroll
    for (int i = 0; i < 4; ++i) av[i] = *(const f16x8*)&acc1[gb + i * 8];

    __syncthreads();   // z reads drained before res overwrites zsR

    // ---------------- Merged epilogue: res->zsR, skip->zsS, one barrier -----
#pragma unroll
    for (int nt = 0; nt < 4; ++nt) {
        int n = ng * 64 + nt * 16 + col;
        float o = ob[n];
#pragma unroll
        for (int mt = 0; mt < 2; ++mt)
#pragma unroll
            for (int reg = 0; reg < 4; ++reg) {
                int r = (mg * 32 + mt * 16 + quad * 4 + reg) * 136 + n;
                zsR[r] = (f16)(acc[mt][nt][reg] + o);
                zsS[r] = (f16)acc[mt][nt + 4][reg];
            }
    }
    __syncthreads();
#pragma unroll
    for (int i = 0; i < 4; ++i) {
        f16x8 rv = *(const f16x8*)&zsR[orow * 136 + oseg * 32 + i * 8];
        *(f16x8*)&h_out[gb + i * 8] = hv[i] + rv;
    }
#pragma unroll
    for (int i = 0; i < 4; ++i) {
        f16x8 sv = *(const f16x8*)&zsS[orow * 136 + oseg * 32 + i * 8];
        *(f16x8*)&acc1[gb + i * 8] = av[i] + sv;
    }
}

// out[bt] = o2b + sum_r o2w[r] * tanh(acc1[bt][r] + o1b[r]); one wave per bt
__global__ __launch_bounds__(256) void final_kernel(
    const f16* __restrict__ acc1, const float* __restrict__ b1,
    const float* __restrict__ w2, const float* __restrict__ b2,
    float* __restrict__ out)
{
    int lane = threadIdx.x & 63;
    int w = threadIdx.x >> 6;
    int bt = blockIdx.x * 4 + w;
    float v0 = (float)acc1[(size_t)bt * 128 + lane];
    float v1 = (float)acc1[(size_t)bt * 128 + lane + 64];
    float s = w2[lane] * fast_tanh(v0 + b1[lane]) +
              w2[lane + 64] * fast_tanh(v1 + b1[lane + 64]);
#pragma unroll
    for (int k = 1; k < 64; k <<= 1) s += __shfl_xor(s, k, 64);
    if (lane == 0) out[bt] = s + b2[0];
}

extern "C" void kernel_launch(void* const* d_in, const int* in_sizes, int n_in,
                              void* d_out, int out_size, void* d_ws, size_t ws_size,
                              hipStream_t stream)
{
    const float* x   = (const float*)d_in[0];
    const float* iw  = (const float*)d_in[1];
    const float* ib  = (const float*)d_in[2];
    const float* cw  = (const float*)d_in[3];
    const float* cb  = (const float*)d_in[4];
    const float* ow  = (const float*)d_in[5];
    const float* ob  = (const float*)d_in[6];
    const float* o1w = (const float*)d_in[7];
    const float* o1b = (const float*)d_in[8];
    const float* o2w = (const float*)d_in[9];
    const float* o2b = (const float*)d_in[10];
    float* out = (float*)d_out;

    const size_t HTR = (size_t)BATCH * T_LEN * 128;   // 16777216
    f16* hA   = (f16*)d_ws;
    f16* hB   = hA + HTR;
    f16* acc1 = hB + HTR;
    f16* wAp  = acc1 + HTR;
    f16* wBp  = wAp + (size_t)NLAYER * 12 * 256 * 32;
    // total ~ 3*32 MB + 2.4 MB = ~103 MB of ws

    prep_weights<<<4608, 256, 0, stream>>>(cw, ow, o1w, wAp, wBp);
    input_init<<<65536, 256, 0, stream>>>(x, iw, ib, hA, acc1);

    const int DIL[NLAYER] = {1, 2, 4, 8, 16, 32, 64, 128, 256};
    f16* hin = hA; f16* hout = hB;
    for (int l = 0; l < NLAYER; ++l) {
        layer_kernel<<<dim3(T_LEN / 64, BATCH), 256, 0, stream>>>(
            hin, hout, acc1,
            wAp + (size_t)l * 12 * 256 * 32, wBp + (size_t)l * 4 * 256 * 32,
            cb + l * 256, ob + l * 128, DIL[l]);
        f16* tmp = hin; hin = hout; hout = tmp;
    }
    final_kernel<<<BATCH * T_LEN / 4, 256, 0, stream>>>(acc1, o1b, o2w, o2b, out);
}